// Round 8
// baseline (478.712 us; speedup 1.0000x reference)
//
#include <hip/hip_runtime.h>

typedef unsigned short ushort_t;
typedef unsigned int uint32;
typedef __attribute__((ext_vector_type(8))) short short8;
typedef __attribute__((ext_vector_type(4))) float f32x4;
typedef __attribute__((ext_vector_type(2))) float f32x2;

#define HID 256
#define MI 128
// p1 is pre-scaled by ALPHA = 2/ln2, so sim MFMA output = cos*2/ln2 and
// exp(cos/T) = exp2(acc) directly. Edge ln-logit: s = 2*cos = d * ln2.
#define ALPHA 2.8853900817779268f
#define LN2F 0.69314718055994531f

__device__ __forceinline__ float bflo(uint32 u) { return __uint_as_float(u << 16); }
__device__ __forceinline__ float bfhi(uint32 u) { return __uint_as_float(u & 0xffff0000u); }
__device__ __forceinline__ ushort_t f2bf(float f) {
  uint32 u = __float_as_uint(f);
  u += 0x7fffu + ((u >> 16) & 1u);   // RNE
  return (ushort_t)(u >> 16);
}

// ---------------------------------------------------------------------------
// Kernel 0 (prep): Wt[n][k] (bf16) <- W[k][n] (f32); zero out[0].
// ---------------------------------------------------------------------------
__global__ __launch_bounds__(256) void prep_kernel(
    const float* __restrict__ W, ushort_t* __restrict__ Wtb,
    float* __restrict__ out)
{
  int idx = blockIdx.x * 256 + threadIdx.x;
  if (idx < HID * MI) {
    int k = idx >> 7, nn = idx & 127;
    Wtb[nn * HID + k] = f2bf(W[k * MI + nn]);   // read coalesced over nn
  }
  if (idx == 0) out[0] = 0.f;
}

// ---------------------------------------------------------------------------
// Kernel 1: p = l2norm(relu(h @ W + b)) -> bf16 (p1 additionally * ALPHA).
// Also zeroes the 7n accumulator floats (spare parallelism; sim runs after).
// ---------------------------------------------------------------------------
__global__ __launch_bounds__(256) void proj_kernel(
    const float* __restrict__ h1, const float* __restrict__ h2,
    const ushort_t* __restrict__ Wtb, const float* __restrict__ b,
    ushort_t* __restrict__ p1b, ushort_t* __restrict__ p2b, int n,
    float* __restrict__ fbase, int nz)
{
  __shared__ __align__(16) unsigned char hb[64 * 512];   // 64 rows x 256 bf16
  int t = threadIdx.x;
  int gid = blockIdx.x * 256 + t;
  if (gid < nz) fbase[gid] = 0.f;    // zero accumulators for sim/edge

  int lane = t & 63, w = t >> 6;
  int lr = lane & 15, lg = lane >> 4;
  long R0 = (long)blockIdx.x * 64;
  const float* src = (R0 < n) ? (h1 + R0 * HID) : (h2 + (R0 - n) * HID);
  ushort_t* dst = (R0 < n) ? (p1b + R0 * MI) : (p2b + (R0 - n) * MI);
  float scale = (R0 < n) ? ALPHA : 1.0f;

  float bb[8];
  #pragma unroll
  for (int ch = 0; ch < 8; ++ch) bb[ch] = b[ch * 16 + lr];

  // Stage + convert: 4096 float4 reads, swizzled bf16 writes.
  const float4* g4 = (const float4*)src;
  #pragma unroll
  for (int i = 0; i < 16; ++i) {
    int idx4 = i * 256 + t;
    float4 v = g4[idx4];
    int row = idx4 >> 6;             // 64 float4 per 256-elem row
    int k0 = (idx4 & 63) * 4;
    int gr = k0 >> 3;                // 16B granule index (8 bf16)
    int off = row * 512 + ((gr ^ (row & 15)) << 4) + (k0 & 7) * 2;
    uint32 lo = (uint32)f2bf(v.x) | ((uint32)f2bf(v.y) << 16);
    uint32 hi = (uint32)f2bf(v.z) | ((uint32)f2bf(v.w) << 16);
    uint2 pk; pk.x = lo; pk.y = hi;
    *(uint2*)(hb + off) = pk;
  }
  __syncthreads();

  short8 afr[8];
  #pragma unroll
  for (int kt = 0; kt < 8; ++kt) {
    int row = w * 16 + lr;
    int g = kt * 4 + lg;
    afr[kt] = *(const short8*)(hb + row * 512 + ((g ^ (row & 15)) << 4));
  }

  f32x4 acc[8];
  #pragma unroll
  for (int ch = 0; ch < 8; ++ch) acc[ch] = (f32x4){0.f, 0.f, 0.f, 0.f};
  #pragma unroll
  for (int ch = 0; ch < 8; ++ch) {
    #pragma unroll
    for (int kt = 0; kt < 8; ++kt) {
      short8 bf = *(const short8*)(Wtb + (size_t)(ch * 16 + lr) * HID + kt * 32 + lg * 8);
      acc[ch] = __builtin_amdgcn_mfma_f32_16x16x32_bf16(afr[kt], bf, acc[ch], 0, 0, 0);
    }
  }

  // Epilogue: rows w*16 + lg*4 + r, cols ch*16 + lr.
  #pragma unroll
  for (int r = 0; r < 4; ++r) {
    float v[8];
    float ss = 0.f;
    #pragma unroll
    for (int ch = 0; ch < 8; ++ch) {
      v[ch] = fmaxf(acc[ch][r] + bb[ch], 0.f);
      ss += v[ch] * v[ch];
    }
    ss += __shfl_xor(ss, 1, 64);
    ss += __shfl_xor(ss, 2, 64);
    ss += __shfl_xor(ss, 4, 64);
    ss += __shfl_xor(ss, 8, 64);
    float rn = rsqrtf(ss) * scale;
    int row = w * 16 + lg * 4 + r;
    #pragma unroll
    for (int ch = 0; ch < 8; ++ch)
      dst[(size_t)row * MI + ch * 16 + lr] = f2bf(v[ch] * rn);
  }
}

// ---------------------------------------------------------------------------
// Kernel 2: fused sim sweep + edge gather.
// sim blocks (y < gridDim.y-1): 512 thr = 8 waves x 64 rows (rt=4: each LDS
// B-frag feeds 4 MFMAs -> DS-pipe work halved vs r7). Block owns 512 rows x
// 1024 cols; B tiles (64 cols, 16 KB) via global->VGPR->ds_write dbuf.
// A frags + rowsums in registers for the whole sweep. Col partials ->
// colacc LDS (ds-atomic, halved count), flushed once.
// edge blocks (y == gridDim.y-1, 16 blocks): grid-stride 4-lane-per-edge
// gather; concurrent with sim (read-only p1b/p2b, disjoint atomic outputs).
// ---------------------------------------------------------------------------
__global__ __launch_bounds__(512, 4) void sim_edge_kernel(
    const ushort_t* __restrict__ p1b, const ushort_t* __restrict__ p2b,
    float* __restrict__ rowsum, float* __restrict__ colsum,
    const int* __restrict__ pos_row, const int* __restrict__ pos_col,
    float* __restrict__ psum1, float* __restrict__ psum2,
    float* __restrict__ srow1, float* __restrict__ srow2,
    float* __restrict__ cntb, int E)
{
  __shared__ __align__(16) unsigned char ldsB[32768];   // 2 x 16 KB dbuf
  __shared__ float colacc[1024];                        // 4 KB
  int t = threadIdx.x;

  if (blockIdx.y == gridDim.y - 1) {
    // ---- edge path: 16 blocks, grid-stride over E*4 lane-slots ----
    int lim = E * 4;
    for (int idx = blockIdx.x * 512 + t; idx < lim; idx += 16 * 512) {
      int e = idx >> 2, q = idx & 3;
      int r = pos_row[e], c = pos_col[e];
      const uint4* a1 = (const uint4*)(p1b + (size_t)r * MI) + q * 4;
      const uint4* b1 = (const uint4*)(p2b + (size_t)c * MI) + q * 4;
      const uint4* a2 = (const uint4*)(p1b + (size_t)c * MI) + q * 4;
      const uint4* b2 = (const uint4*)(p2b + (size_t)r * MI) + q * 4;
      float d1 = 0.f, d2 = 0.f;
      #pragma unroll
      for (int it = 0; it < 4; ++it) {
        uint4 x = a1[it], y = b1[it];
        d1 += bflo(x.x) * bflo(y.x) + bfhi(x.x) * bfhi(y.x);
        d1 += bflo(x.y) * bflo(y.y) + bfhi(x.y) * bfhi(y.y);
        d1 += bflo(x.z) * bflo(y.z) + bfhi(x.z) * bfhi(y.z);
        d1 += bflo(x.w) * bflo(y.w) + bfhi(x.w) * bfhi(y.w);
        uint4 u = a2[it], v = b2[it];
        d2 += bflo(u.x) * bflo(v.x) + bfhi(u.x) * bfhi(v.x);
        d2 += bflo(u.y) * bflo(v.y) + bfhi(u.y) * bfhi(v.y);
        d2 += bflo(u.z) * bflo(v.z) + bfhi(u.z) * bfhi(v.z);
        d2 += bflo(u.w) * bflo(v.w) + bfhi(u.w) * bfhi(v.w);
      }
      d1 += __shfl_xor(d1, 1, 64);
      d1 += __shfl_xor(d1, 2, 64);
      d2 += __shfl_xor(d2, 1, 64);
      d2 += __shfl_xor(d2, 2, 64);
      if (q == 0) {
        float e1 = __builtin_amdgcn_exp2f(d1);
        float e2 = __builtin_amdgcn_exp2f(d2);
        atomicAdd(&psum1[r], e1);
        atomicAdd(&srow1[r], d1 * LN2F);
        atomicAdd(&psum2[r], e2);
        atomicAdd(&srow2[r], d2 * LN2F);
        atomicAdd(&cntb[r], 1.0f);
      }
    }
    return;
  }

  // ---- sim path ----
  int lane = t & 63, w = t >> 6;          // 8 waves
  int lr = lane & 15, lg = lane >> 4;
  int rowbase = blockIdx.y * 512 + w * 64;   // wave owns 64 fixed rows
  int jbase = blockIdx.x * 1024;             // block owns 1024 cols

  // Staging registers: 2 granules of 16B per thread per tile.
  uint4 st0, st1;
  int row0 = t >> 4, gs0 = t & 15;
  int g1 = t + 512;
  int row1 = g1 >> 4, gs1 = g1 & 15;

  auto load_stage = [&](int jt) {
    int j0 = jbase + jt * 64;
    st0 = *(const uint4*)(p2b + (size_t)(j0 + row0) * MI + (gs0 << 3));
    st1 = *(const uint4*)(p2b + (size_t)(j0 + row1) * MI + (gs1 << 3));
  };
  auto write_stage = [&](int buf) {
    *(uint4*)(ldsB + buf * 16384 + row0 * 256 + ((gs0 ^ (row0 & 15)) << 4)) = st0;
    *(uint4*)(ldsB + buf * 16384 + row1 * 256 + ((gs1 ^ (row1 & 15)) << 4)) = st1;
  };

  load_stage(0);

  // A frags: 64 rows x K=128 in registers (64 VGPRs) for the whole kernel.
  short8 afr[4][4];
  #pragma unroll
  for (int rt = 0; rt < 4; ++rt)
    #pragma unroll
    for (int kt = 0; kt < 4; ++kt)
      afr[rt][kt] = *(const short8*)(p1b + (size_t)(rowbase + rt * 16 + lr) * MI + kt * 32 + lg * 8);

  colacc[t] = 0.f;
  colacc[512 + t] = 0.f;

  f32x2 rs2[4][2];
  #pragma unroll
  for (int rt = 0; rt < 4; ++rt) {
    rs2[rt][0] = (f32x2){0.f, 0.f};
    rs2[rt][1] = (f32x2){0.f, 0.f};
  }

  write_stage(0);
  __syncthreads();   // tile 0 staged, colacc zeroed

  for (int jt = 0; jt < 16; ++jt) {
    int cur = jt & 1;
    if (jt + 1 < 16) load_stage(jt + 1);   // global->VGPR, covered by compute
    const unsigned char* B = ldsB + cur * 16384;

    #pragma unroll
    for (int ch = 0; ch < 4; ++ch) {
      f32x4 acc[4];
      #pragma unroll
      for (int rt = 0; rt < 4; ++rt) acc[rt] = (f32x4){0.f, 0.f, 0.f, 0.f};
      #pragma unroll
      for (int kt = 0; kt < 4; ++kt) {
        int ncol = ch * 16 + lr;
        int g = kt * 4 + lg;
        short8 bf = *(const short8*)(B + ncol * 256 + ((g ^ (ncol & 15)) << 4));
        #pragma unroll
        for (int rt = 0; rt < 4; ++rt)
          acc[rt] = __builtin_amdgcn_mfma_f32_16x16x32_bf16(afr[rt][kt], bf, acc[rt], 0, 0, 0);
      }
      // D layout: col = ch*16 + lr, row = rt*16 + lg*4 + reg.
      f32x2 cs2 = (f32x2){0.f, 0.f};
      #pragma unroll
      for (int rt = 0; rt < 4; ++rt) {
        f32x2 e01, e23;
        e01[0] = __builtin_amdgcn_exp2f(acc[rt][0]);
        e01[1] = __builtin_amdgcn_exp2f(acc[rt][1]);
        e23[0] = __builtin_amdgcn_exp2f(acc[rt][2]);
        e23[1] = __builtin_amdgcn_exp2f(acc[rt][3]);
        rs2[rt][0] += e01;
        rs2[rt][1] += e23;
        cs2 += e01;
        cs2 += e23;
      }
      // Column partial: reduce over the 4 lg groups, ds-atomic by lg==0.
      float csum = cs2[0] + cs2[1];
      csum += __shfl_xor(csum, 16, 64);
      csum += __shfl_xor(csum, 32, 64);
      if (lg == 0) atomicAdd(&colacc[jt * 64 + ch * 16 + lr], csum);
    }
    if (jt + 1 < 16) write_stage(1 - cur);  // vmcnt wait here (covered)
    __syncthreads();
  }

  // Row flush: butterfly over the 16 lr-lanes, one global atomic per row.
  #pragma unroll
  for (int rt = 0; rt < 4; ++rt)
    #pragma unroll
    for (int j = 0; j < 2; ++j)
      #pragma unroll
      for (int s = 0; s < 2; ++s) {
        float v = rs2[rt][j][s];
        v += __shfl_xor(v, 1, 64);
        v += __shfl_xor(v, 2, 64);
        v += __shfl_xor(v, 4, 64);
        v += __shfl_xor(v, 8, 64);
        if (lr == 0) atomicAdd(&rowsum[rowbase + rt * 16 + lg * 4 + j * 2 + s], v);
      }

  // Col flush: one global atomic per owned col.
  atomicAdd(&colsum[jbase + t], colacc[t]);
  atomicAdd(&colsum[jbase + 512 + t], colacc[512 + t]);
}

// ---------------------------------------------------------------------------
// Kernel 3: loss contribution per row, atomicAdd into out[0] (pre-zeroed).
// ---------------------------------------------------------------------------
__global__ __launch_bounds__(256) void finalize_kernel(
    const float* __restrict__ rowsum, const float* __restrict__ colsum,
    const float* __restrict__ psum1, const float* __restrict__ psum2,
    const float* __restrict__ srow1, const float* __restrict__ srow2,
    const float* __restrict__ cntb, float* __restrict__ out, int n)
{
  __shared__ float sred[4];
  int r = blockIdx.x * 256 + threadIdx.x;
  float local = 0.f;
  if (r < n) {
    float inv = 1.0f / cntb[r];
    float d1 = rowsum[r] - psum1[r];
    float d2 = colsum[r] - psum2[r];
    local = srow1[r] * inv - __builtin_amdgcn_logf(d1) * LN2F
          + srow2[r] * inv - __builtin_amdgcn_logf(d2) * LN2F;
  }
  #pragma unroll
  for (int m = 1; m <= 32; m <<= 1) local += __shfl_xor(local, m, 64);
  int lane = threadIdx.x & 63, wv = threadIdx.x >> 6;
  if (lane == 0) sred[wv] = local;
  __syncthreads();
  if (threadIdx.x == 0) {
    float tot = sred[0] + sred[1] + sred[2] + sred[3];
    atomicAdd(out, -tot / (2.0f * n));
  }
}

extern "C" void kernel_launch(void* const* d_in, const int* in_sizes, int n_in,
                              void* d_out, int out_size, void* d_ws, size_t ws_size,
                              hipStream_t stream)
{
  const float* h1 = (const float*)d_in[0];
  const float* h2 = (const float*)d_in[1];
  const float* W  = (const float*)d_in[2];
  const float* b  = (const float*)d_in[3];
  const int* pos_row = (const int*)d_in[4];
  const int* pos_col = (const int*)d_in[5];
  int n = in_sizes[0] / HID;      // 16384
  int E = in_sizes[4];            // 65536
  float* out = (float*)d_out;

  char* ws = (char*)d_ws;
  ushort_t* p1b = (ushort_t*)ws;                       // n*128 bf16 = 4 MB
  ushort_t* p2b = p1b + (size_t)n * MI;                // 4 MB
  float* fbase  = (float*)(ws + (size_t)2 * n * MI * sizeof(ushort_t));
  float* rowsum = fbase;
  float* colsum = rowsum + n;
  float* psum1  = colsum + n;
  float* psum2  = psum1 + n;
  float* srow1  = psum2 + n;
  float* srow2  = srow1 + n;
  float* cntb   = srow2 + n;
  ushort_t* Wtb = (ushort_t*)(cntb + n);               // 128x256 bf16 = 64 KB

  int nz = 7 * n;
  prep_kernel<<<(HID * MI + 255) / 256, 256, 0, stream>>>(W, Wtb, out);
  proj_kernel<<<2 * n / 64, 256, 0, stream>>>(h1, h2, Wtb, b, p1b, p2b, n,
                                              fbase, nz);
  dim3 g2(n / 1024, n / 512 + 1);  // (16 colgroups, 32 rowgroups + 1 edge row)
  sim_edge_kernel<<<g2, 512, 0, stream>>>(p1b, p2b, rowsum, colsum,
                                          pos_row, pos_col,
                                          psum1, psum2, srow1, srow2, cntb, E);
  finalize_kernel<<<(n + 255) / 256, 256, 0, stream>>>(rowsum, colsum, psum1, psum2,
                                                       srow1, srow2, cntb, out, n);
}

// Round 9
// 235.368 us; speedup vs baseline: 2.0339x; 2.0339x over previous
//
#include <hip/hip_runtime.h>

typedef unsigned short ushort_t;
typedef unsigned int uint32;
typedef __attribute__((ext_vector_type(8))) short short8;
typedef __attribute__((ext_vector_type(4))) float f32x4;
typedef __attribute__((ext_vector_type(2))) float f32x2;

#define HID 256
#define MI 128
// p1 is pre-scaled by ALPHA = 2/ln2, so sim MFMA output = cos*2/ln2 and
// exp(cos/T) = exp2(acc) directly. Edge ln-logit: s = 2*cos = d * ln2.
#define ALPHA 2.8853900817779268f
#define LN2F 0.69314718055994531f

__device__ __forceinline__ float bflo(uint32 u) { return __uint_as_float(u << 16); }
__device__ __forceinline__ float bfhi(uint32 u) { return __uint_as_float(u & 0xffff0000u); }
__device__ __forceinline__ ushort_t f2bf(float f) {
  uint32 u = __float_as_uint(f);
  u += 0x7fffu + ((u >> 16) & 1u);   // RNE
  return (ushort_t)(u >> 16);
}
// f32 -> fp8 e4m3fn (RNE), input in [0, 448) (ours: [0, 2.9]); no builtin risk.
__device__ __forceinline__ uint32 f2fp8(float f) {
  if (f < 0.015625f) return (uint32)__float2int_rn(f * 512.0f);  // denorm (8 -> 0x08 = 2^-6, correct)
  uint32 u = __float_as_uint(f);
  u += 0x7FFFFu + ((u >> 20) & 1u);  // RNE at bit 20 (3-bit mantissa)
  return ((u >> 20) - 960u) & 0xFFu; // rebias: (E'-120)<<3 | M3
}

// ---------------------------------------------------------------------------
// Kernel 0 (prep): Wt[n][k] (bf16) <- W[k][n] (f32); zero out[0].
// ---------------------------------------------------------------------------
__global__ __launch_bounds__(256) void prep_kernel(
    const float* __restrict__ W, ushort_t* __restrict__ Wtb,
    float* __restrict__ out)
{
  int idx = blockIdx.x * 256 + threadIdx.x;
  if (idx < HID * MI) {
    int k = idx >> 7, nn = idx & 127;
    Wtb[nn * HID + k] = f2bf(W[k * MI + nn]);   // read coalesced over nn
  }
  if (idx == 0) out[0] = 0.f;
}

// ---------------------------------------------------------------------------
// Kernel 1: p = l2norm(relu(h @ W + b)); writes bf16 (edges) AND fp8 (sim).
// p1 pre-scaled by ALPHA in both forms. Also zeroes the 7n accumulators.
// ---------------------------------------------------------------------------
__global__ __launch_bounds__(256) void proj_kernel(
    const float* __restrict__ h1, const float* __restrict__ h2,
    const ushort_t* __restrict__ Wtb, const float* __restrict__ b,
    ushort_t* __restrict__ p1h, ushort_t* __restrict__ p2h,
    unsigned char* __restrict__ p1f, unsigned char* __restrict__ p2f, int n,
    float* __restrict__ fbase, int nz)
{
  __shared__ __align__(16) unsigned char hb[64 * 512];   // 64 rows x 256 bf16
  int t = threadIdx.x;
  int gid = blockIdx.x * 256 + t;
  if (gid < nz) fbase[gid] = 0.f;    // zero accumulators for sim/edge

  int lane = t & 63, w = t >> 6;
  int lr = lane & 15, lg = lane >> 4;
  long R0 = (long)blockIdx.x * 64;
  const float* src = (R0 < n) ? (h1 + R0 * HID) : (h2 + (R0 - n) * HID);
  ushort_t* dsth = (R0 < n) ? (p1h + R0 * MI) : (p2h + (R0 - n) * MI);
  unsigned char* dstf = (R0 < n) ? (p1f + R0 * MI) : (p2f + (R0 - n) * MI);
  float scale = (R0 < n) ? ALPHA : 1.0f;

  float bb[8];
  #pragma unroll
  for (int ch = 0; ch < 8; ++ch) bb[ch] = b[ch * 16 + lr];

  // Stage + convert: 4096 float4 reads, swizzled bf16 writes.
  const float4* g4 = (const float4*)src;
  #pragma unroll
  for (int i = 0; i < 16; ++i) {
    int idx4 = i * 256 + t;
    float4 v = g4[idx4];
    int row = idx4 >> 6;             // 64 float4 per 256-elem row
    int k0 = (idx4 & 63) * 4;
    int gr = k0 >> 3;                // 16B granule index (8 bf16)
    int off = row * 512 + ((gr ^ (row & 15)) << 4) + (k0 & 7) * 2;
    uint32 lo = (uint32)f2bf(v.x) | ((uint32)f2bf(v.y) << 16);
    uint32 hi = (uint32)f2bf(v.z) | ((uint32)f2bf(v.w) << 16);
    uint2 pk; pk.x = lo; pk.y = hi;
    *(uint2*)(hb + off) = pk;
  }
  __syncthreads();

  short8 afr[8];
  #pragma unroll
  for (int kt = 0; kt < 8; ++kt) {
    int row = w * 16 + lr;
    int g = kt * 4 + lg;
    afr[kt] = *(const short8*)(hb + row * 512 + ((g ^ (row & 15)) << 4));
  }

  f32x4 acc[8];
  #pragma unroll
  for (int ch = 0; ch < 8; ++ch) acc[ch] = (f32x4){0.f, 0.f, 0.f, 0.f};
  #pragma unroll
  for (int ch = 0; ch < 8; ++ch) {
    #pragma unroll
    for (int kt = 0; kt < 8; ++kt) {
      short8 bf = *(const short8*)(Wtb + (size_t)(ch * 16 + lr) * HID + kt * 32 + lg * 8);
      acc[ch] = __builtin_amdgcn_mfma_f32_16x16x32_bf16(afr[kt], bf, acc[ch], 0, 0, 0);
    }
  }

  // Epilogue: rows w*16 + lg*4 + r, cols ch*16 + lr.
  #pragma unroll
  for (int r = 0; r < 4; ++r) {
    float v[8];
    float ss = 0.f;
    #pragma unroll
    for (int ch = 0; ch < 8; ++ch) {
      v[ch] = fmaxf(acc[ch][r] + bb[ch], 0.f);
      ss += v[ch] * v[ch];
    }
    ss += __shfl_xor(ss, 1, 64);
    ss += __shfl_xor(ss, 2, 64);
    ss += __shfl_xor(ss, 4, 64);
    ss += __shfl_xor(ss, 8, 64);
    float rn = rsqrtf(ss) * scale;
    int row = w * 16 + lg * 4 + r;
    #pragma unroll
    for (int ch = 0; ch < 8; ++ch) {
      float pv = v[ch] * rn;
      dsth[(size_t)row * MI + ch * 16 + lr] = f2bf(pv);
      dstf[(size_t)row * MI + ch * 16 + lr] = (unsigned char)f2fp8(pv);
    }
  }
}

// ---------------------------------------------------------------------------
// Kernel 2: fused sim sweep (fp8) + edge gather (bf16).
// sim blocks: 512 thr = 8 waves x 64 rows (rt=4 viable in fp8: afr = 32
// VGPRs). Block owns 512 rows x 512 cols; B tiles (64 cols x 128 K fp8 =
// 8 KB) via global->VGPR->ds_write dbuf. MFMA: 16x16x32_fp8_fp8 (bf16 rate,
// half fragment bytes -> DS reads halved AND rt=4 fits registers).
// LDS 8-B-granule XOR swizzle: slot g^(col&15) -> conflict-free b64 reads.
// A frags + rowsums in registers; col partials -> colacc (2 KB), one flush.
// edge blocks (y == gridDim.y-1): grid-stride 4-lane-per-edge bf16 gather.
// ---------------------------------------------------------------------------
__global__ __launch_bounds__(512, 2) void sim_edge_kernel(
    const unsigned char* __restrict__ p1f, const unsigned char* __restrict__ p2f,
    const ushort_t* __restrict__ p1h, const ushort_t* __restrict__ p2h,
    float* __restrict__ rowsum, float* __restrict__ colsum,
    const int* __restrict__ pos_row, const int* __restrict__ pos_col,
    float* __restrict__ psum1, float* __restrict__ psum2,
    float* __restrict__ srow1, float* __restrict__ srow2,
    float* __restrict__ cntb, int E)
{
  __shared__ __align__(16) unsigned char ldsB[16384];   // 2 x 8 KB dbuf
  __shared__ float colacc[512];                         // 2 KB
  int t = threadIdx.x;

  if (blockIdx.y == gridDim.y - 1) {
    // ---- edge path: 32 blocks, grid-stride over E*4 lane-slots ----
    int lim = E * 4;
    for (int idx = blockIdx.x * 512 + t; idx < lim; idx += 32 * 512) {
      int e = idx >> 2, q = idx & 3;
      int r = pos_row[e], c = pos_col[e];
      const uint4* a1 = (const uint4*)(p1h + (size_t)r * MI) + q * 4;
      const uint4* b1 = (const uint4*)(p2h + (size_t)c * MI) + q * 4;
      const uint4* a2 = (const uint4*)(p1h + (size_t)c * MI) + q * 4;
      const uint4* b2 = (const uint4*)(p2h + (size_t)r * MI) + q * 4;
      float d1 = 0.f, d2 = 0.f;
      #pragma unroll
      for (int it = 0; it < 4; ++it) {
        uint4 x = a1[it], y = b1[it];
        d1 += bflo(x.x) * bflo(y.x) + bfhi(x.x) * bfhi(y.x);
        d1 += bflo(x.y) * bflo(y.y) + bfhi(x.y) * bfhi(y.y);
        d1 += bflo(x.z) * bflo(y.z) + bfhi(x.z) * bfhi(y.z);
        d1 += bflo(x.w) * bflo(y.w) + bfhi(x.w) * bfhi(y.w);
        uint4 u = a2[it], v = b2[it];
        d2 += bflo(u.x) * bflo(v.x) + bfhi(u.x) * bfhi(v.x);
        d2 += bflo(u.y) * bflo(v.y) + bfhi(u.y) * bfhi(v.y);
        d2 += bflo(u.z) * bflo(v.z) + bfhi(u.z) * bfhi(v.z);
        d2 += bflo(u.w) * bflo(v.w) + bfhi(u.w) * bfhi(v.w);
      }
      d1 += __shfl_xor(d1, 1, 64);
      d1 += __shfl_xor(d1, 2, 64);
      d2 += __shfl_xor(d2, 1, 64);
      d2 += __shfl_xor(d2, 2, 64);
      if (q == 0) {
        float e1 = __builtin_amdgcn_exp2f(d1);
        float e2 = __builtin_amdgcn_exp2f(d2);
        atomicAdd(&psum1[r], e1);
        atomicAdd(&srow1[r], d1 * LN2F);
        atomicAdd(&psum2[r], e2);
        atomicAdd(&srow2[r], d2 * LN2F);
        atomicAdd(&cntb[r], 1.0f);
      }
    }
    return;
  }

  // ---- sim path ----
  int lane = t & 63, w = t >> 6;          // 8 waves
  int lr = lane & 15, lg = lane >> 4;
  int rowbase = blockIdx.y * 512 + w * 64;   // wave owns 64 fixed rows
  int jbase = blockIdx.x * 512;              // block owns 512 cols

  // Staging: thread t owns 16-B granule t of the 8 KB tile.
  int sj = t >> 3, sg = t & 7;               // tile row (col j), 16B granule
  uint4 stv;
  auto load_stage = [&](int jt) {            // coalesced global read
    stv = *(const uint4*)(p2f + (size_t)(jbase + jt * 64 + sj) * MI + sg * 16);
  };
  // 8-B slot s holds global granule s^(sj&15). The 16-B value covers 8-B
  // granules {2sg, 2sg+1}: slots {2sg^m, (2sg^m)^1} with m = sj&15 — a
  // contiguous 16-B pair, halves swapped when sj is odd.
  auto write_stage = [&](int buf) {
    uint4 v = stv;
    int s0 = (2 * sg) ^ (sj & 15);
    if (s0 & 1) { uint32 x = v.x, y = v.y; v.x = v.z; v.y = v.w; v.z = x; v.w = y; }
    *(uint4*)(ldsB + buf * 8192 + sj * 128 + (s0 & ~1) * 8) = v;
  };

  load_stage(0);

  // A frags: 64 rows x K=128 fp8 in registers (32 VGPRs) for the whole kernel.
  long afr[4][4];
  #pragma unroll
  for (int rt = 0; rt < 4; ++rt)
    #pragma unroll
    for (int kt = 0; kt < 4; ++kt)
      afr[rt][kt] = *(const long*)(p1f + (size_t)(rowbase + rt * 16 + lr) * MI + kt * 32 + lg * 8);

  colacc[t] = 0.f;

  f32x2 rs2[4][2];
  #pragma unroll
  for (int rt = 0; rt < 4; ++rt) {
    rs2[rt][0] = (f32x2){0.f, 0.f};
    rs2[rt][1] = (f32x2){0.f, 0.f};
  }

  write_stage(0);
  __syncthreads();   // tile 0 staged, colacc zeroed

  for (int jt = 0; jt < 8; ++jt) {
    int cur = jt & 1;
    if (jt + 1 < 8) load_stage(jt + 1);   // global->VGPR, covered by compute
    const unsigned char* B = ldsB + cur * 8192;

    #pragma unroll
    for (int ch = 0; ch < 4; ++ch) {
      f32x4 acc[4];
      #pragma unroll
      for (int rt = 0; rt < 4; ++rt) acc[rt] = (f32x4){0.f, 0.f, 0.f, 0.f};
      #pragma unroll
      for (int kt = 0; kt < 4; ++kt) {
        int ncol = ch * 16 + lr;
        long bf = *(const long*)(B + ncol * 128 + (((kt * 4 + lg) ^ lr) << 3));
        #pragma unroll
        for (int rt = 0; rt < 4; ++rt)
          acc[rt] = __builtin_amdgcn_mfma_f32_16x16x32_fp8_fp8(afr[rt][kt], bf, acc[rt], 0, 0, 0);
      }
      // D layout: col = ch*16 + lr, row = rt*16 + lg*4 + reg.
      f32x2 cs2 = (f32x2){0.f, 0.f};
      #pragma unroll
      for (int rt = 0; rt < 4; ++rt) {
        f32x2 e01, e23;
        e01[0] = __builtin_amdgcn_exp2f(acc[rt][0]);
        e01[1] = __builtin_amdgcn_exp2f(acc[rt][1]);
        e23[0] = __builtin_amdgcn_exp2f(acc[rt][2]);
        e23[1] = __builtin_amdgcn_exp2f(acc[rt][3]);
        rs2[rt][0] += e01;
        rs2[rt][1] += e23;
        cs2 += e01;
        cs2 += e23;
      }
      // Column partial: reduce over the 4 lg groups, ds-atomic by lg==0.
      float csum = cs2[0] + cs2[1];
      csum += __shfl_xor(csum, 16, 64);
      csum += __shfl_xor(csum, 32, 64);
      if (lg == 0) atomicAdd(&colacc[jt * 64 + ch * 16 + lr], csum);
    }
    if (jt + 1 < 8) write_stage(1 - cur);  // vmcnt wait here (covered)
    __syncthreads();
  }

  // Row flush: butterfly over the 16 lr-lanes, one global atomic per row.
  #pragma unroll
  for (int rt = 0; rt < 4; ++rt)
    #pragma unroll
    for (int j = 0; j < 2; ++j)
      #pragma unroll
      for (int s = 0; s < 2; ++s) {
        float v = rs2[rt][j][s];
        v += __shfl_xor(v, 1, 64);
        v += __shfl_xor(v, 2, 64);
        v += __shfl_xor(v, 4, 64);
        v += __shfl_xor(v, 8, 64);
        if (lr == 0) atomicAdd(&rowsum[rowbase + rt * 16 + lg * 4 + j * 2 + s], v);
      }

  // Col flush: one global atomic per owned col.
  atomicAdd(&colsum[jbase + t], colacc[t]);
}

// ---------------------------------------------------------------------------
// Kernel 3: loss contribution per row, atomicAdd into out[0] (pre-zeroed).
// ---------------------------------------------------------------------------
__global__ __launch_bounds__(256) void finalize_kernel(
    const float* __restrict__ rowsum, const float* __restrict__ colsum,
    const float* __restrict__ psum1, const float* __restrict__ psum2,
    const float* __restrict__ srow1, const float* __restrict__ srow2,
    const float* __restrict__ cntb, float* __restrict__ out, int n)
{
  __shared__ float sred[4];
  int r = blockIdx.x * 256 + threadIdx.x;
  float local = 0.f;
  if (r < n) {
    float inv = 1.0f / cntb[r];
    float d1 = rowsum[r] - psum1[r];
    float d2 = colsum[r] - psum2[r];
    local = srow1[r] * inv - __builtin_amdgcn_logf(d1) * LN2F
          + srow2[r] * inv - __builtin_amdgcn_logf(d2) * LN2F;
  }
  #pragma unroll
  for (int m = 1; m <= 32; m <<= 1) local += __shfl_xor(local, m, 64);
  int lane = threadIdx.x & 63, wv = threadIdx.x >> 6;
  if (lane == 0) sred[wv] = local;
  __syncthreads();
  if (threadIdx.x == 0) {
    float tot = sred[0] + sred[1] + sred[2] + sred[3];
    atomicAdd(out, -tot / (2.0f * n));
  }
}

extern "C" void kernel_launch(void* const* d_in, const int* in_sizes, int n_in,
                              void* d_out, int out_size, void* d_ws, size_t ws_size,
                              hipStream_t stream)
{
  const float* h1 = (const float*)d_in[0];
  const float* h2 = (const float*)d_in[1];
  const float* W  = (const float*)d_in[2];
  const float* b  = (const float*)d_in[3];
  const int* pos_row = (const int*)d_in[4];
  const int* pos_col = (const int*)d_in[5];
  int n = in_sizes[0] / HID;      // 16384
  int E = in_sizes[4];            // 65536
  float* out = (float*)d_out;

  char* ws = (char*)d_ws;
  ushort_t* p1h = (ushort_t*)ws;                       // n*128 bf16 = 4 MB
  ushort_t* p2h = p1h + (size_t)n * MI;                // 4 MB
  unsigned char* p1f = (unsigned char*)(p2h + (size_t)n * MI);  // 2 MB
  unsigned char* p2f = p1f + (size_t)n * MI;                    // 2 MB
  float* fbase  = (float*)(p2f + (size_t)n * MI);
  float* rowsum = fbase;
  float* colsum = rowsum + n;
  float* psum1  = colsum + n;
  float* psum2  = psum1 + n;
  float* srow1  = psum2 + n;
  float* srow2  = srow1 + n;
  float* cntb   = srow2 + n;
  ushort_t* Wtb = (ushort_t*)(cntb + n);               // 128x256 bf16 = 64 KB

  int nz = 7 * n;
  prep_kernel<<<(HID * MI + 255) / 256, 256, 0, stream>>>(W, Wtb, out);
  proj_kernel<<<2 * n / 64, 256, 0, stream>>>(h1, h2, Wtb, b, p1h, p2h,
                                              p1f, p2f, n, fbase, nz);
  dim3 g2(n / 512, n / 512 + 1);  // (32 colgroups, 32 rowgroups + 1 edge row)
  sim_edge_kernel<<<g2, 512, 0, stream>>>(p1f, p2f, p1h, p2h, rowsum, colsum,
                                          pos_row, pos_col,
                                          psum1, psum2, srow1, srow2, cntb, E);
  finalize_kernel<<<(n + 255) / 256, 256, 0, stream>>>(rowsum, colsum, psum1, psum2,
                                                       srow1, srow2, cntb, out, n);
}